// Round 14
// baseline (46.666 us; speedup 1.0000x reference)
//
#include <hip/hip_runtime.h>
#include <hip/hip_bf16.h>
#include <math.h>

// AdaptiveContrastiveLoss: x[4096][512] f32 -> scalar f32.
// R13: epilogue atomics again. R12 proved LDS-atomic serialization was
// ~75us of the 105us "GEMM" time. Now: per-WAVE privatized count
// histograms (4 copies, zero inter-wave collisions) made affordable by
// packing bin pairs (b, b+1024) into u32 halves (low<=32K so no carry;
// hot bins pair with cold bins -> no new collisions). 4x4KB = 16KB,
// total LDS 48.9KB -> still 3 blocks/CU. Rest identical to R12.
// ws: xnb 4MB | slice_cnt 4.3MB | slice_top 2.1KB | cnt_part 32KB.

#define N 4096
#define D 512
#define NN 16777216u
#define NBF 2048         // uniform value bins over [-1,1]
#define NSLICE 528       // upper-triangle 128x128 tiles of 4096^2

typedef __attribute__((ext_vector_type(8))) short bf16x8;
typedef __attribute__((ext_vector_type(4))) float f32x4;
typedef const __attribute__((address_space(1))) void gas_t;  // global
typedef __attribute__((address_space(3))) void las_t;        // LDS

// monotone value->bin: floor((s+1)*1024), clamped to [0, NBF-1].
// bin edge at s==0 is exact, so bin >= 1024 <=> s >= 0.
__device__ __forceinline__ int val2bin(float s) {
  int b = (int)fmaf(s, 1024.0f, 1024.0f);
  return b < 0 ? 0 : (b > NBF - 1 ? NBF - 1 : b);
}
__device__ __forceinline__ unsigned short f2bf(float f) {  // RNE
  unsigned int u = __float_as_uint(f);
  u += 0x7FFFu + ((u >> 16) & 1u);
  return (unsigned short)(u >> 16);
}

// ---- 1) row norms + normalize + f32->bf16 convert ----
__global__ __launch_bounds__(256) void norm_conv(const float* __restrict__ x,
                                                 unsigned short* __restrict__ xnb) {
  const int row = blockIdx.x;
  const int tid = threadIdx.x;
  const float2 v = ((const float2*)(x + (size_t)row * D))[tid];
  float s = v.x * v.x + v.y * v.y;
#pragma unroll
  for (int o = 32; o > 0; o >>= 1) s += __shfl_xor(s, o);
  __shared__ float wsum[4];
  __shared__ float s_rinv;
  if ((tid & 63) == 0) wsum[tid >> 6] = s;
  __syncthreads();
  if (tid == 0) {
    float t = wsum[0] + wsum[1] + wsum[2] + wsum[3];
    s_rinv = 1.0f / fmaxf(sqrtf(t), 1e-8f);
  }
  __syncthreads();
  const float r = s_rinv;
  ((ushort2*)(xnb + (size_t)row * D))[tid] = make_ushort2(f2bf(v.x * r), f2bf(v.y * r));
}

// ---- 2) fused GEMM + packed per-wave count bins, 128x128 tile, 4 waves ----
#define BM 128
#define BK 64
__global__ __launch_bounds__(256, 3) void gemm_fused(const unsigned short* __restrict__ xnb,
                                                     unsigned int* __restrict__ slice_cnt,
                                                     float* __restrict__ slice_top) {
  // triangular decode: linear block id -> (bx, by), bx <= by
  const int bid = blockIdx.x;
  int by = (int)((sqrtf(8.0f * (float)bid + 1.0f) - 1.0f) * 0.5f);
  while ((by + 1) * (by + 2) / 2 <= bid) ++by;
  while (by * (by + 1) / 2 > bid) --by;
  const int bx = bid - by * (by + 1) / 2;

  __shared__ unsigned short As[BM][BK];   // linear row-major, 128B rows
  __shared__ unsigned short Bs[BM][BK];
  __shared__ unsigned int cntp[4][NBF / 2];  // per-wave; u32 = {hi: b+1024, lo: b}
  __shared__ float stop;                  // exact sum fmax(1-s,0), top bin
  const int tid = threadIdx.x;
  for (int i = tid; i < 4 * (NBF / 2); i += 256) ((unsigned int*)cntp)[i] = 0u;
  if (tid == 0) stop = 0.f;

  const int w = tid >> 6, l = tid & 63;
  const int wr = w >> 1, wc = w & 1;       // wave grid 2x2; wave = 64x64
  const int lr = l & 15, kgrp = l >> 4;
  const int swz = lr & 7;                  // read-side XOR swizzle
  const int bm = bx * BM, bn = by * BM;

  // staging (R11): wave w stages rows [w*32, w*32+32); LDS dest linear,
  // global source pre-swizzled: lane l -> granule (l&7)^(l>>3) of row l>>3.
  const int srow = l >> 3;
  const int gsrc = (l & 7) ^ srow;
  const unsigned short* srcA0 = xnb + (size_t)(bm + w * 32 + srow) * D + gsrc * 8;
  const unsigned short* srcB0 = xnb + (size_t)(bn + w * 32 + srow) * D + gsrc * 8;

  f32x4 acc[4][4] = {};

  for (int kt = 0; kt < D; kt += BK) {
    __syncthreads();  // previous iter's LDS reads done (and cnt init, iter 0)
#pragma unroll
    for (int c = 0; c < 4; ++c) {
      __builtin_amdgcn_global_load_lds((gas_t*)(srcA0 + (size_t)c * 8 * D + kt),
                                       (las_t*)&As[w * 32 + c * 8][0], 16, 0, 0);
      __builtin_amdgcn_global_load_lds((gas_t*)(srcB0 + (size_t)c * 8 * D + kt),
                                       (las_t*)&Bs[w * 32 + c * 8][0], 16, 0, 0);
    }
    __syncthreads();  // drains vmcnt: staged data visible
#pragma unroll
    for (int kk = 0; kk < BK; kk += 32) {
      const int g0 = (kk >> 3) + kgrp;     // logical k-granule 0..7
      bf16x8 af[4], bf4[4];
#pragma unroll
      for (int m = 0; m < 4; ++m)
        af[m] = *(const bf16x8*)&As[wr * 64 + m * 16 + lr][(g0 ^ swz) * 8];
#pragma unroll
      for (int n = 0; n < 4; ++n)
        bf4[n] = *(const bf16x8*)&Bs[wc * 64 + n * 16 + lr][(g0 ^ swz) * 8];
#pragma unroll
      for (int m = 0; m < 4; ++m)
#pragma unroll
        for (int n = 0; n < 4; ++n)
          acc[m][n] = __builtin_amdgcn_mfma_f32_16x16x32_bf16(af[m], bf4[n], acc[m][n], 0, 0, 0);
    }
  }

  // epilogue: packed count binning, one histogram copy per wave.
  // add wg to low half (b < 1024) or wg<<16 to high half (b >= 1024);
  // low half max 2*16384 = 32768 < 65536 -> never carries into high.
  const unsigned int wg = (bx == by) ? 1u : 2u;
  __syncthreads();
#pragma unroll
  for (int m = 0; m < 4; ++m)
#pragma unroll
    for (int n = 0; n < 4; ++n)
#pragma unroll
      for (int e = 0; e < 4; ++e) {
        const float s = acc[m][n][e];
        const int b = val2bin(s);
        const unsigned int val = (b & 1024) ? (wg << 16) : wg;
        atomicAdd(&cntp[w][b & 1023], val);
        if (b == NBF - 1) atomicAdd(&stop, (float)wg * fmaxf(1.0f - s, 0.0f));
      }
  __syncthreads();
  // deterministic flush: unpack + sum 4 copies, plain stores to private slice
  unsigned int* oc = slice_cnt + (size_t)bid * NBF;
  for (int i = tid; i < NBF / 2; i += 256) {
    const unsigned int c0 = cntp[0][i], c1 = cntp[1][i];
    const unsigned int c2 = cntp[2][i], c3 = cntp[3][i];
    oc[i]            = (c0 & 0xFFFFu) + (c1 & 0xFFFFu) + (c2 & 0xFFFFu) + (c3 & 0xFFFFu);
    oc[i + NBF / 2]  = (c0 >> 16) + (c1 >> 16) + (c2 >> 16) + (c3 >> 16);
  }
  if (tid == 0) slice_top[bid] = stop;
}

// ---- 3) tree-reduce slices: 8192 threads, thread = (chunk c, bin b) ----
__global__ __launch_bounds__(256) void reduce_bins(const unsigned int* __restrict__ slice_cnt,
                                                   unsigned int* __restrict__ cnt_part) {
  const int t = blockIdx.x * 256 + threadIdx.x;  // 0..8191
  const int b = t & (NBF - 1);
  const int c = t >> 11;                         // 0..3, 132 slices each
  const int s0 = c * (NSLICE / 4);
  unsigned int cs = 0;
#pragma unroll 4
  for (int s = 0; s < NSLICE / 4; ++s)
    cs += slice_cnt[(size_t)(s0 + s) * NBF + b];
  cnt_part[t] = cs;   // layout [c][b]
}

// ---- 4) finalize: prefix over bins, threshold bins, midpoint range sums ----
__global__ __launch_bounds__(256) void final_loss(const unsigned int* __restrict__ cnt_part,
                                                  const float* __restrict__ slice_top,
                                                  float* __restrict__ out,
                                                  unsigned int kneg, unsigned int kpos) {
  __shared__ unsigned int part[256], Q[256];
  __shared__ unsigned int sbp, sbn;
  __shared__ double tstage[4];
  __shared__ double dstage[2][4];
  __shared__ unsigned int ustage[2][4];
  const int tid = threadIdx.x;
  const int lane = tid & 63, wid = tid >> 6;

  // gather this thread's 8 bins (sum the 4 chunk partials; fixed order)
  unsigned int c8[8];
  unsigned int tot = 0;
#pragma unroll
  for (int j = 0; j < 8; ++j) {
    const int b = tid * 8 + j;
    unsigned int cc = 0;
#pragma unroll
    for (int c = 0; c < 4; ++c) cc += cnt_part[c * NBF + b];
    c8[j] = cc; tot += cc;
  }
  // top-bin exact pos-term sum over slices
  {
    float tl = 0.f;
    for (int s = tid; s < NSLICE; s += 256) tl += slice_top[s];
    double td = tl;
#pragma unroll
    for (int o = 32; o > 0; o >>= 1) td += __shfl_xor(td, o);
    if (lane == 0) tstage[wid] = td;
  }
  // prefix scan over per-thread counts
  part[tid] = tot;
  Q[tid] = tot;
  __syncthreads();
#pragma unroll
  for (int off = 1; off < 256; off <<= 1) {
    unsigned int t2 = (tid >= off) ? Q[tid - off] : 0u;
    __syncthreads();
    Q[tid] += t2;
    __syncthreads();
  }
  const unsigned int total = Q[255];
  const unsigned int incl = Q[tid];
  const unsigned int excl = incl - part[tid];
  const unsigned int targets[2] = {kpos, kneg};
#pragma unroll
  for (int t = 0; t < 2; ++t) {
    const unsigned int r = (total == 0u) ? 0u
                         : (targets[t] < total ? targets[t] : total - 1u);
    if (total != 0u && excl <= r && r < incl) {  // exactly one owner
      unsigned int rr = r - excl, cum = 0;
      int bsel = -1;
#pragma unroll
      for (int j = 0; j < 8; ++j) {
        if (bsel < 0 && cum + c8[j] > rr) bsel = j;
        else if (bsel < 0) cum += c8[j];
      }
      if (bsel < 0) bsel = 7;
      if (t == 0) sbp = tid * 8 + (unsigned int)bsel;
      else        sbn = tid * 8 + (unsigned int)bsel;
    }
  }
  __syncthreads();
  const double topsum = tstage[0] + tstage[1] + tstage[2] + tstage[3];
  const unsigned int bp = sbp, bn = sbn;

  // midpoint range sums:
  //   pos: sum over bins > bp of cnt * (1 - mid)  [top bin: exact topsum]
  //   neg: sum over bins < bn of cnt * fmax(mid, 0)
  double psum = 0.0, nsum = 0.0;
  unsigned int pcnt = 0, ncnt = 0;
#pragma unroll
  for (int j = 0; j < 8; ++j) {
    const unsigned int b = tid * 8 + j;
    const double mid = ((double)b + 0.5) / 1024.0 - 1.0;
    if (b > bp) {
      pcnt += c8[j];
      psum += (b == NBF - 1) ? topsum : (double)c8[j] * (1.0 - mid);
    }
    if (b < bn) {
      ncnt += c8[j];
      if (mid > 0.0) nsum += (double)c8[j] * mid;
    }
  }
#pragma unroll
  for (int o = 32; o > 0; o >>= 1) {
    psum += __shfl_xor(psum, o);
    nsum += __shfl_xor(nsum, o);
    pcnt += __shfl_xor(pcnt, o);
    ncnt += __shfl_xor(ncnt, o);
  }
  if (lane == 0) {
    dstage[0][wid] = psum; dstage[1][wid] = nsum;
    ustage[0][wid] = pcnt; ustage[1][wid] = ncnt;
  }
  __syncthreads();
  if (tid == 0) {
    const double ps = dstage[0][0] + dstage[0][1] + dstage[0][2] + dstage[0][3];
    const double ns = dstage[1][0] + dstage[1][1] + dstage[1][2] + dstage[1][3];
    const unsigned int pc = ustage[0][0] + ustage[0][1] + ustage[0][2] + ustage[0][3];
    const unsigned int nc = ustage[1][0] + ustage[1][1] + ustage[1][2] + ustage[1][3];
    const double pl = pc ? ps / (double)pc : 0.0;
    const double nl = nc ? ns / (double)nc : 0.0;
    out[0] = (float)(pl + nl);
  }
}

extern "C" void kernel_launch(void* const* d_in, const int* in_sizes, int n_in,
                              void* d_out, int out_size, void* d_ws, size_t ws_size,
                              hipStream_t stream) {
  const float* x = (const float*)d_in[0];
  float* out = (float*)d_out;
  char* ws = (char*)d_ws;

  unsigned short* xnb = (unsigned short*)ws;                       // 4 MB
  size_t off = (size_t)N * D * 2;
  unsigned int* slice_cnt = (unsigned int*)(ws + off);             // 4.3 MB
  off += (size_t)NSLICE * NBF * 4;
  float* slice_top = (float*)(ws + off);                           // 2.1 KB
  off += (size_t)NSLICE * 4;
  off = (off + 255) & ~(size_t)255;
  unsigned int* cnt_part = (unsigned int*)(ws + off);              // 32 KB

  const unsigned int kneg = (unsigned int)ceil((double)NN * 0.2);          // 3355444
  const unsigned int kpos = (unsigned int)ceil((double)NN * (1.0 - 0.2));  // 13421773

  norm_conv<<<N, 256, 0, stream>>>(x, xnb);
  gemm_fused<<<NSLICE, 256, 0, stream>>>(xnb, slice_cnt, slice_top);
  reduce_bins<<<32, 256, 0, stream>>>(slice_cnt, cnt_part);
  final_loss<<<1, 256, 0, stream>>>(cnt_part, slice_top, out, kneg, kpos);
}

// Round 15
// 42.193 us; speedup vs baseline: 1.1060x; 1.1060x over previous
//
#include <hip/hip_runtime.h>
#include <hip/hip_bf16.h>
#include <math.h>

// AdaptiveContrastiveLoss: x[4096][512] f32 -> scalar f32.
// R14: consolidation. R13 (per-wave packed hist) was neutral -> epilogue
// atomics saturated; remaining fat is kernel-count/overhead. (a) reduce_bins
// deleted: gemm flushes straight to a global hist via integer atomicAdd
// (order-independent = deterministic); (b) norm_conv rewritten wave-per-row
// (no LDS, no block syncs); (c) epilogue reverted to R12's plain 2-copy.
// Pipeline: memset(8KB) -> norm_conv -> gemm_fused -> final_loss.
// ws: xnb 4MB | hist 8KB | slice_top 2.1KB.

#define N 4096
#define D 512
#define NN 16777216u
#define NBF 2048         // uniform value bins over [-1,1]
#define NSLICE 528       // upper-triangle 128x128 tiles of 4096^2

typedef __attribute__((ext_vector_type(8))) short bf16x8;
typedef __attribute__((ext_vector_type(4))) float f32x4;
typedef const __attribute__((address_space(1))) void gas_t;  // global
typedef __attribute__((address_space(3))) void las_t;        // LDS

// monotone value->bin: floor((s+1)*1024), clamped to [0, NBF-1].
// bin edge at s==0 is exact, so bin >= 1024 <=> s >= 0.
__device__ __forceinline__ int val2bin(float s) {
  int b = (int)fmaf(s, 1024.0f, 1024.0f);
  return b < 0 ? 0 : (b > NBF - 1 ? NBF - 1 : b);
}
__device__ __forceinline__ unsigned short f2bf(float f) {  // RNE
  unsigned int u = __float_as_uint(f);
  u += 0x7FFFu + ((u >> 16) & 1u);
  return (unsigned short)(u >> 16);
}

// ---- 1) row norms + normalize + bf16 convert: one WAVE per row ----
__global__ __launch_bounds__(256) void norm_conv(const float* __restrict__ x,
                                                 unsigned short* __restrict__ xnb) {
  const int row = blockIdx.x * 4 + (threadIdx.x >> 6);  // 4 waves/block
  const int l = threadIdx.x & 63;
  const float4* rp = (const float4*)(x + (size_t)row * D);
  const float4 v0 = rp[l * 2];
  const float4 v1 = rp[l * 2 + 1];
  float s = v0.x * v0.x + v0.y * v0.y + v0.z * v0.z + v0.w * v0.w +
            v1.x * v1.x + v1.y * v1.y + v1.z * v1.z + v1.w * v1.w;
#pragma unroll
  for (int o = 32; o > 0; o >>= 1) s += __shfl_xor(s, o);
  const float r = 1.0f / fmaxf(sqrtf(s), 1e-8f);
  bf16x8 o8;
  o8[0] = (short)f2bf(v0.x * r); o8[1] = (short)f2bf(v0.y * r);
  o8[2] = (short)f2bf(v0.z * r); o8[3] = (short)f2bf(v0.w * r);
  o8[4] = (short)f2bf(v1.x * r); o8[5] = (short)f2bf(v1.y * r);
  o8[6] = (short)f2bf(v1.z * r); o8[7] = (short)f2bf(v1.w * r);
  *(bf16x8*)&xnb[(size_t)row * D + l * 8] = o8;
}

// ---- 2) fused GEMM + count bins, 128x128 tile, 4 waves; global-hist flush ----
#define BM 128
#define BK 64
__global__ __launch_bounds__(256, 3) void gemm_fused(const unsigned short* __restrict__ xnb,
                                                     unsigned int* __restrict__ hist,
                                                     float* __restrict__ slice_top) {
  // triangular decode: linear block id -> (bx, by), bx <= by
  const int bid = blockIdx.x;
  int by = (int)((sqrtf(8.0f * (float)bid + 1.0f) - 1.0f) * 0.5f);
  while ((by + 1) * (by + 2) / 2 <= bid) ++by;
  while (by * (by + 1) / 2 > bid) --by;
  const int bx = bid - by * (by + 1) / 2;

  __shared__ unsigned short As[BM][BK];   // linear row-major, 128B rows
  __shared__ unsigned short Bs[BM][BK];
  __shared__ unsigned int cnt[2][NBF];    // privatized per wave-pair (R12)
  __shared__ float stop;                  // exact sum fmax(1-s,0), top bin
  const int tid = threadIdx.x;
  for (int i = tid; i < 2 * NBF; i += 256) ((unsigned int*)cnt)[i] = 0u;
  if (tid == 0) stop = 0.f;

  const int w = tid >> 6, l = tid & 63;
  const int wr = w >> 1, wc = w & 1;       // wave grid 2x2; wave = 64x64
  const int lr = l & 15, kgrp = l >> 4;
  const int swz = lr & 7;                  // read-side XOR swizzle
  const int hc = w >> 1;                   // histogram copy (0 or 1)
  const int bm = bx * BM, bn = by * BM;

  // staging (R11): wave w stages rows [w*32, w*32+32); LDS dest linear,
  // global source pre-swizzled: lane l -> granule (l&7)^(l>>3) of row l>>3.
  const int srow = l >> 3;
  const int gsrc = (l & 7) ^ srow;
  const unsigned short* srcA0 = xnb + (size_t)(bm + w * 32 + srow) * D + gsrc * 8;
  const unsigned short* srcB0 = xnb + (size_t)(bn + w * 32 + srow) * D + gsrc * 8;

  f32x4 acc[4][4] = {};

  for (int kt = 0; kt < D; kt += BK) {
    __syncthreads();  // previous iter's LDS reads done (and cnt init, iter 0)
#pragma unroll
    for (int c = 0; c < 4; ++c) {
      __builtin_amdgcn_global_load_lds((gas_t*)(srcA0 + (size_t)c * 8 * D + kt),
                                       (las_t*)&As[w * 32 + c * 8][0], 16, 0, 0);
      __builtin_amdgcn_global_load_lds((gas_t*)(srcB0 + (size_t)c * 8 * D + kt),
                                       (las_t*)&Bs[w * 32 + c * 8][0], 16, 0, 0);
    }
    __syncthreads();  // drains vmcnt: staged data visible
#pragma unroll
    for (int kk = 0; kk < BK; kk += 32) {
      const int g0 = (kk >> 3) + kgrp;     // logical k-granule 0..7
      bf16x8 af[4], bf4[4];
#pragma unroll
      for (int m = 0; m < 4; ++m)
        af[m] = *(const bf16x8*)&As[wr * 64 + m * 16 + lr][(g0 ^ swz) * 8];
#pragma unroll
      for (int n = 0; n < 4; ++n)
        bf4[n] = *(const bf16x8*)&Bs[wc * 64 + n * 16 + lr][(g0 ^ swz) * 8];
#pragma unroll
      for (int m = 0; m < 4; ++m)
#pragma unroll
        for (int n = 0; n < 4; ++n)
          acc[m][n] = __builtin_amdgcn_mfma_f32_16x16x32_bf16(af[m], bf4[n], acc[m][n], 0, 0, 0);
    }
  }

  // epilogue: count-only binning (1 LDS atomic per value, 2-way privatized)
  const unsigned int wg = (bx == by) ? 1u : 2u;
  __syncthreads();
#pragma unroll
  for (int m = 0; m < 4; ++m)
#pragma unroll
    for (int n = 0; n < 4; ++n)
#pragma unroll
      for (int e = 0; e < 4; ++e) {
        const float s = acc[m][n][e];
        const int b = val2bin(s);
        atomicAdd(&cnt[hc][b], wg);
        if (b == NBF - 1) atomicAdd(&stop, (float)wg * fmaxf(1.0f - s, 0.0f));
      }
  __syncthreads();
  // flush: integer global atomics (order-independent -> deterministic);
  // skip zero bins so only ~hot bins generate traffic.
  for (int i = tid; i < NBF; i += 256) {
    const unsigned int c = cnt[0][i] + cnt[1][i];
    if (c) atomicAdd(&hist[i], c);
  }
  if (tid == 0) slice_top[bid] = stop;
}

// ---- 3) finalize: prefix over bins, threshold bins, midpoint range sums ----
__global__ __launch_bounds__(256) void final_loss(const unsigned int* __restrict__ hist,
                                                  const float* __restrict__ slice_top,
                                                  float* __restrict__ out,
                                                  unsigned int kneg, unsigned int kpos) {
  __shared__ unsigned int part[256], Q[256];
  __shared__ unsigned int sbp, sbn;
  __shared__ double tstage[4];
  __shared__ double dstage[2][4];
  __shared__ unsigned int ustage[2][4];
  const int tid = threadIdx.x;
  const int lane = tid & 63, wid = tid >> 6;

  // gather this thread's 8 bins
  unsigned int c8[8];
  unsigned int tot = 0;
#pragma unroll
  for (int j = 0; j < 8; ++j) {
    c8[j] = hist[tid * 8 + j];
    tot += c8[j];
  }
  // top-bin exact pos-term sum over slices
  {
    float tl = 0.f;
    for (int s = tid; s < NSLICE; s += 256) tl += slice_top[s];
    double td = tl;
#pragma unroll
    for (int o = 32; o > 0; o >>= 1) td += __shfl_xor(td, o);
    if (lane == 0) tstage[wid] = td;
  }
  // prefix scan over per-thread counts
  part[tid] = tot;
  Q[tid] = tot;
  __syncthreads();
#pragma unroll
  for (int off = 1; off < 256; off <<= 1) {
    unsigned int t2 = (tid >= off) ? Q[tid - off] : 0u;
    __syncthreads();
    Q[tid] += t2;
    __syncthreads();
  }
  const unsigned int total = Q[255];
  const unsigned int incl = Q[tid];
  const unsigned int excl = incl - part[tid];
  const unsigned int targets[2] = {kpos, kneg};
#pragma unroll
  for (int t = 0; t < 2; ++t) {
    const unsigned int r = (total == 0u) ? 0u
                         : (targets[t] < total ? targets[t] : total - 1u);
    if (total != 0u && excl <= r && r < incl) {  // exactly one owner
      unsigned int rr = r - excl, cum = 0;
      int bsel = -1;
#pragma unroll
      for (int j = 0; j < 8; ++j) {
        if (bsel < 0 && cum + c8[j] > rr) bsel = j;
        else if (bsel < 0) cum += c8[j];
      }
      if (bsel < 0) bsel = 7;
      if (t == 0) sbp = tid * 8 + (unsigned int)bsel;
      else        sbn = tid * 8 + (unsigned int)bsel;
    }
  }
  __syncthreads();
  const double topsum = tstage[0] + tstage[1] + tstage[2] + tstage[3];
  const unsigned int bp = sbp, bn = sbn;

  // midpoint range sums:
  //   pos: sum over bins > bp of cnt * (1 - mid)  [top bin: exact topsum]
  //   neg: sum over bins < bn of cnt * fmax(mid, 0)
  double psum = 0.0, nsum = 0.0;
  unsigned int pcnt = 0, ncnt = 0;
#pragma unroll
  for (int j = 0; j < 8; ++j) {
    const unsigned int b = tid * 8 + j;
    const double mid = ((double)b + 0.5) / 1024.0 - 1.0;
    if (b > bp) {
      pcnt += c8[j];
      psum += (b == NBF - 1) ? topsum : (double)c8[j] * (1.0 - mid);
    }
    if (b < bn) {
      ncnt += c8[j];
      if (mid > 0.0) nsum += (double)c8[j] * mid;
    }
  }
#pragma unroll
  for (int o = 32; o > 0; o >>= 1) {
    psum += __shfl_xor(psum, o);
    nsum += __shfl_xor(nsum, o);
    pcnt += __shfl_xor(pcnt, o);
    ncnt += __shfl_xor(ncnt, o);
  }
  if (lane == 0) {
    dstage[0][wid] = psum; dstage[1][wid] = nsum;
    ustage[0][wid] = pcnt; ustage[1][wid] = ncnt;
  }
  __syncthreads();
  if (tid == 0) {
    const double ps = dstage[0][0] + dstage[0][1] + dstage[0][2] + dstage[0][3];
    const double ns = dstage[1][0] + dstage[1][1] + dstage[1][2] + dstage[1][3];
    const unsigned int pc = ustage[0][0] + ustage[0][1] + ustage[0][2] + ustage[0][3];
    const unsigned int nc = ustage[1][0] + ustage[1][1] + ustage[1][2] + ustage[1][3];
    const double pl = pc ? ps / (double)pc : 0.0;
    const double nl = nc ? ns / (double)nc : 0.0;
    out[0] = (float)(pl + nl);
  }
}

extern "C" void kernel_launch(void* const* d_in, const int* in_sizes, int n_in,
                              void* d_out, int out_size, void* d_ws, size_t ws_size,
                              hipStream_t stream) {
  const float* x = (const float*)d_in[0];
  float* out = (float*)d_out;
  char* ws = (char*)d_ws;

  unsigned short* xnb = (unsigned short*)ws;                       // 4 MB
  size_t off = (size_t)N * D * 2;
  unsigned int* hist = (unsigned int*)(ws + off);                  // 8 KB
  off += (size_t)NBF * 4;
  float* slice_top = (float*)(ws + off);                           // 2.1 KB

  const unsigned int kneg = (unsigned int)ceil((double)NN * 0.2);          // 3355444
  const unsigned int kpos = (unsigned int)ceil((double)NN * (1.0 - 0.2));  // 13421773

  hipMemsetAsync(hist, 0, (size_t)NBF * 4, stream);
  norm_conv<<<N / 4, 256, 0, stream>>>(x, xnb);
  gemm_fused<<<NSLICE, 256, 0, stream>>>(xnb, hist, slice_top);
  final_loss<<<1, 256, 0, stream>>>(hist, slice_top, out, kneg, kpos);
}